// Round 6
// baseline (1120.042 us; speedup 1.0000x reference)
//
#include <hip/hip_runtime.h>

// VQ argmin: exact bit-level emulation of numpy fp32 reference:
//   A  = np.sum(flat*flat, axis=1)     (numpy pairwise-sum tree, fp32)
//   M2 = (2*flat) @ emb.T              (BLAS: sequential fp32 fma chain over d)
//   dist = (A - M2) + ee;  argmin_k (first-min ties)
// z_e_x: [B=16, D=256, H=64, W=64] fp32; embedding: [K=1024, D=256] fp32
// out: int32 [65536]
//
// R9: LDS-tiled GEMM structure. R8 falsified the SGPR-prefetch theory
// (halving eT SGPR traffic made stall WORSE); the stall is z-load latency
// from L3/HBM, unfixable in the SGPR-broadcast structure (register budget
// proven at 128 by R4/R5 spills). New vq: classic block-tiled GEMM --
// 128n x 128k tile per block, z/eT staged via LDS in 16-d chunks (16 KB),
// 8n x 8k register micro-tile (64 fmaf per 4 ds_read_b128). z is read ONCE
// per block; next chunk's global loads issue before compute (2048-cycle
// cover >> 900cy HBM latency). Exact chain preserved: acc[n][k] accumulates
// d strictly ascending in fp32 fmaf; dist = (An - acc) + ee; (dist,k) u64
// key min = first-min ties (LDS reduce + atomicMin, proven R4/R5/R8).
// Stack kept from R8 (all verified): split a_kernel, tiled et, ee, unpack.

#define D_DIM  256
#define K_DIM  1024
#define HW     4096
#define N_TOT  65536
#define BN     128                // n-tile per block
#define BK     128                // k-tile per block
#define NCH    16                 // d-chunks of 16
#define F32MAX 3.402823466e38f

// ---- numpy pairwise_sum for ||e_k||^2 (n=256 = two 128-blocks of 8 accs)

__global__ void ee_kernel(const float* __restrict__ e, float* __restrict__ ee) {
#pragma clang fp contract(off)
    int k = blockIdx.x * blockDim.x + threadIdx.x;
    if (k >= K_DIM) return;
    const float* row = e + (size_t)k * D_DIM;
    float total = 0.0f;
    #pragma unroll
    for (int h = 0; h < 2; ++h) {
        const float* a = row + h * 128;
        float r[8];
        #pragma unroll
        for (int j = 0; j < 8; ++j) { float v = a[j]; r[j] = v * v; }
        #pragma unroll
        for (int i = 8; i < 128; i += 8) {
            #pragma unroll
            for (int j = 0; j < 8; ++j) { float v = a[i + j]; r[j] = r[j] + v * v; }
        }
        float s = ((r[0] + r[1]) + (r[2] + r[3])) + ((r[4] + r[5]) + (r[6] + r[7]));
        total = (h == 0) ? s : (total + s);
    }
    ee[k] = total;
}

// ---- A = numpy pairwise ||z_n||^2: 2 threads per n, one 128-half each
// (halves are independent 8-acc chains; total = s0 + s1). Bitwise-exact.

__global__ void a_kernel(const float* __restrict__ z, float* __restrict__ A) {
#pragma clang fp contract(off)
    int t = blockIdx.x * blockDim.x + threadIdx.x;   // 0 .. 2*N_TOT-1
    int n = t >> 1;
    int h = t & 1;
    int b  = n >> 12;
    int hw = n & (HW - 1);
    const float* base = z + (size_t)b * D_DIM * HW + hw + (size_t)(h * 128) * HW;
    float r[8];
    #pragma unroll
    for (int j = 0; j < 8; ++j) { float v = base[(size_t)j * HW]; r[j] = v * v; }
    #pragma unroll
    for (int i = 8; i < 128; i += 8) {
        #pragma unroll
        for (int j = 0; j < 8; ++j) {
            float v = base[(size_t)(i + j) * HW];
            r[j] = r[j] + v * v;
        }
    }
    float s = ((r[0] + r[1]) + (r[2] + r[3])) + ((r[4] + r[5]) + (r[6] + r[7]));
    float other = __shfl_xor(s, 1);
    if (h == 0) A[n] = s + other;    // total = s_half0 + s_half1 (exact order)
}

// ---- transpose + fold the exact x2: eT[d][k] = 2*emb[k][d]

__global__ void et_kernel(const float* __restrict__ e, float* __restrict__ eT) {
    __shared__ float t[32][33];
    const int k0 = blockIdx.x * 32;
    const int d0 = blockIdx.y * 32;
    const int tx = threadIdx.x;         // 0..31
    const int ty = threadIdx.y;         // 0..7
    #pragma unroll
    for (int i = 0; i < 32; i += 8)
        t[ty + i][tx] = 2.0f * e[(size_t)(k0 + ty + i) * D_DIM + d0 + tx];
    __syncthreads();
    #pragma unroll
    for (int i = 0; i < 32; i += 8)
        eT[(size_t)(d0 + ty + i) * K_DIM + k0 + tx] = t[tx][ty + i];
}

// ---- main: block = 128n x 128k C-tile; 256 threads = 16(nx) x 16(ky),
// each an 8n x 8k micro-tile. LDS: zs[16d][128n] + es[16d][128k] = 16 KB,
// single-buffered (2 barriers/chunk); chunk c+1's global loads issue before
// compute(c), so HBM latency hides under 2048 FMA-cycles.

__launch_bounds__(256, 4)
__global__ void vq_gemm(const float* __restrict__ z, const float* __restrict__ eT,
                        const float* __restrict__ A, const float* __restrict__ ee,
                        unsigned long long* __restrict__ packed) {
#pragma clang fp contract(off)
    __shared__ __align__(16) float sm[4096];  // zs=[0..2047], es=[2048..4095]
    float* zs = sm;                           // epilogue reuse: u64 red[128][16]
    float* es = sm + 2048;

    const int t     = threadIdx.x;
    const int ntile = blockIdx.x & 511;       // 512 n-tiles
    const int ktile = blockIdx.x >> 9;        // 8 k-tiles
    const int ng0   = ntile * BN;
    const int k0    = ktile * BK;
    const int b     = ng0 >> 12;              // n-tile never spans a batch
    const int hw0   = ng0 & (HW - 1);
    const float* __restrict__ zg = z + (size_t)b * D_DIM * HW + hw0;

    const int nx = t & 15;                    // micro-tile n-group (compute)
    const int ky = t >> 4;                    // micro-tile k-group (compute)
    const int sd = t >> 4;                    // staging d-row 0..15
    const int sn = (t & 15) * 8;              // staging col (8 floats)

    const float* __restrict__ zsrc = zg + (size_t)sd * HW + sn;
    const float* __restrict__ esrc = eT + (size_t)sd * K_DIM + k0 + sn;

    // prologue: load chunk 0 into regs
    float4 la0 = *(const float4*)(zsrc);
    float4 la1 = *(const float4*)(zsrc + 4);
    float4 lb0 = *(const float4*)(esrc);
    float4 lb1 = *(const float4*)(esrc + 4);

    float acc[8][8];
    #pragma unroll
    for (int i = 0; i < 8; ++i)
        #pragma unroll
        for (int j = 0; j < 8; ++j) acc[i][j] = 0.0f;

    #pragma unroll 1
    for (int c = 0; c < NCH; ++c) {
        // stage chunk c into LDS (vmcnt auto-inserted before first write)
        *(float4*)(&zs[sd * 128 + sn])     = la0;
        *(float4*)(&zs[sd * 128 + sn + 4]) = la1;
        *(float4*)(&es[sd * 128 + sn])     = lb0;
        *(float4*)(&es[sd * 128 + sn + 4]) = lb1;
        // issue chunk c+1's global loads now: consumed next iteration,
        // ~2048 issue-cycles of compute below cover the HBM/L3 latency
        if (c + 1 < NCH) {
            const float* zn = zsrc + (size_t)(c + 1) * 16 * HW;
            const float* en = esrc + (size_t)(c + 1) * 16 * K_DIM;
            la0 = *(const float4*)(zn);
            la1 = *(const float4*)(zn + 4);
            lb0 = *(const float4*)(en);
            lb1 = *(const float4*)(en + 4);
        }
        __syncthreads();
        // compute 16 d's: d = c*16 + dd ascending -> exact per-(n,k) chain
        #pragma unroll
        for (int dd = 0; dd < 16; ++dd) {
            float4 z0 = *(const float4*)(&zs[dd * 128 + nx * 8]);
            float4 z1 = *(const float4*)(&zs[dd * 128 + nx * 8 + 4]);
            float4 e0 = *(const float4*)(&es[dd * 128 + ky * 8]);
            float4 e1 = *(const float4*)(&es[dd * 128 + ky * 8 + 4]);
            const float zr[8] = {z0.x, z0.y, z0.z, z0.w, z1.x, z1.y, z1.z, z1.w};
            const float er[8] = {e0.x, e0.y, e0.z, e0.w, e1.x, e1.y, e1.z, e1.w};
            #pragma unroll
            for (int i = 0; i < 8; ++i)
                #pragma unroll
                for (int j = 0; j < 8; ++j)
                    acc[i][j] = fmaf(zr[i], er[j], acc[i][j]);
        }
        __syncthreads();   // protect sm before next chunk's overwrite
    }

    // ---- epilogue: dist = (An - M2) + ee; per-n best over this block's
    // 128 k's via u64 (distbits, k) keys: LDS reduce over 16 ky-groups,
    // then one device atomicMin per n. Key order == first-min semantics.
    unsigned long long* red = (unsigned long long*)sm;  // [128][16]
    #pragma unroll
    for (int i = 0; i < 8; ++i) {
        const int n_l = nx * 8 + i;
        const float An = A[ng0 + n_l];
        float bv = F32MAX;
        int   bk = 0;
        #pragma unroll
        for (int j = 0; j < 8; ++j) {
            const int k = k0 + ky * 8 + j;     // j ascending -> k ascending
            const float dist = (An - acc[i][j]) + ee[k];
            if (dist < bv) { bv = dist; bk = k; }
        }
        unsigned int vb = __float_as_uint(bv);
        vb = (vb & 0x80000000u) ? ~vb : (vb | 0x80000000u);
        red[n_l * 16 + ky] = ((unsigned long long)vb << 32) | (unsigned int)bk;
    }
    __syncthreads();
    if (t < BN) {
        unsigned long long m = red[t * 16];
        #pragma unroll
        for (int q = 1; q < 16; ++q) {
            const unsigned long long v = red[t * 16 + q];
            if (v < m) m = v;
        }
        atomicMin(&packed[ng0 + t], m);
    }
}

__global__ void unpack_kernel(const unsigned long long* __restrict__ packed,
                              int* __restrict__ out) {
    int n = blockIdx.x * blockDim.x + threadIdx.x;
    out[n] = (int)(packed[n] & 0xFFFFFFFFull);
}

extern "C" void kernel_launch(void* const* d_in, const int* in_sizes, int n_in,
                              void* d_out, int out_size, void* d_ws, size_t ws_size,
                              hipStream_t stream) {
    const float* z   = (const float*)d_in[0];   // [16,256,64,64]
    const float* emb = (const float*)d_in[1];   // [1024,256]
    int* out = (int*)d_out;                     // [65536] int32

    float* wsEE = (float*)d_ws;                     // 1024
    float* wsA  = wsEE + K_DIM;                     // 65536
    float* wsET = wsA + N_TOT;                      // 262144
    unsigned long long* wsPacked =
        (unsigned long long*)(wsET + (size_t)D_DIM * K_DIM);  // 65536 u64

    hipMemsetAsync(wsPacked, 0xFF, (size_t)N_TOT * sizeof(unsigned long long),
                   stream);
    et_kernel<<<dim3(K_DIM / 32, D_DIM / 32), dim3(32, 8), 0, stream>>>(emb, wsET);
    ee_kernel<<<K_DIM / 256, 256, 0, stream>>>(emb, wsEE);
    a_kernel<<<2 * N_TOT / 256, 256, 0, stream>>>(z, wsA);
    vq_gemm<<<(N_TOT / BN) * (K_DIM / BK), 256, 0, stream>>>(z, wsET, wsA, wsEE,
                                                             wsPacked);
    unpack_kernel<<<N_TOT / 256, 256, 0, stream>>>(wsPacked, out);
}